// Round 1
// baseline (398.002 us; speedup 1.0000x reference)
//
#include <hip/hip_runtime.h>

namespace {
constexpr int NB = 64;    // batches
constexpr int NS = 196;   // sites
constexpr int ND = 64;    // bond dim
constexpr int HALF = 98;
constexpr int NO = 10;

__global__ __launch_bounds__(128) void mps_kernel(
    const float* __restrict__ x,      // [B][S][2]
    const float* __restrict__ cores,  // [S][D][D][2]
    const float* __restrict__ oc,     // [O][D][D]
    float* __restrict__ out)          // [B][O]
{
    __shared__ __align__(16) float lbuf[ND];
    __shared__ __align__(16) float rbuf[ND];

    const int b    = blockIdx.x;
    const int tid  = threadIdx.x;
    const int wave = tid >> 6;   // 0 = left chain, 1 = right chain
    const int lane = tid & 63;
    const float* xb = x + b * (NS * 2);

    if (wave == 0) {
        // lvec = e0^T * M_0 * M_1 * ... * M_97   (row-vector propagation)
        lbuf[lane] = (lane == 0) ? 1.0f : 0.0f;
        const float* cbase = cores + lane * 2;          // column r = lane
        for (int s = 0; s < HALF; ++s) {
            const float* cs = cbase + s * (ND * ND * 2);
            const float x0 = xb[2 * s], x1 = xb[2 * s + 1];
            float a0 = 0.f, a1 = 0.f, b0 = 0.f, b1 = 0.f;
            #pragma unroll
            for (int l = 0; l < ND; l += 4) {
                const float4 v4 = *(const float4*)(lbuf + l);       // LDS broadcast
                const float2 p0 = *(const float2*)(cs + (l + 0) * (ND * 2));
                const float2 p1 = *(const float2*)(cs + (l + 1) * (ND * 2));
                const float2 p2 = *(const float2*)(cs + (l + 2) * (ND * 2));
                const float2 p3 = *(const float2*)(cs + (l + 3) * (ND * 2));
                a0 = fmaf(v4.x, p0.x, a0); b0 = fmaf(v4.x, p0.y, b0);
                a1 = fmaf(v4.y, p1.x, a1); b1 = fmaf(v4.y, p1.y, b1);
                a0 = fmaf(v4.z, p2.x, a0); b0 = fmaf(v4.z, p2.y, b0);
                a1 = fmaf(v4.w, p3.x, a1); b1 = fmaf(v4.w, p3.y, b1);
            }
            const float vn = x0 * (a0 + a1) + x1 * (b0 + b1);
            // in-wave lockstep + in-order LDS => all reads above completed
            lbuf[lane] = vn;
        }
    } else {
        // rvec = M_98 * ... * M_195 * e0   (column-vector propagation, backwards)
        rbuf[lane] = (lane == 0) ? 1.0f : 0.0f;
        const float* cbase = cores + lane * (ND * 2);   // row l = lane (contiguous over r)
        for (int s = NS - 1; s >= HALF; --s) {
            const float* cs = cbase + s * (ND * ND * 2);
            const float x0 = xb[2 * s], x1 = xb[2 * s + 1];
            float a0 = 0.f, a1 = 0.f, b0 = 0.f, b1 = 0.f;
            #pragma unroll
            for (int r = 0; r < ND; r += 4) {
                const float4 w4 = *(const float4*)(rbuf + r);       // LDS broadcast
                const float4 q0 = *(const float4*)(cs + 2 * r);     // (c0,c1) for r, r+1
                const float4 q1 = *(const float4*)(cs + 2 * r + 4); // (c0,c1) for r+2, r+3
                a0 = fmaf(w4.x, q0.x, a0); b0 = fmaf(w4.x, q0.y, b0);
                a1 = fmaf(w4.y, q0.z, a1); b1 = fmaf(w4.y, q0.w, b1);
                a0 = fmaf(w4.z, q1.x, a0); b0 = fmaf(w4.z, q1.y, b0);
                a1 = fmaf(w4.w, q1.z, a1); b1 = fmaf(w4.w, q1.w, b1);
            }
            const float wn = x0 * (a0 + a1) + x1 * (b0 + b1);
            rbuf[lane] = wn;
        }
    }
    __syncthreads();

    // out[b,o] = sum_i lvec[i] * (sum_j oc[o,i,j] * rvec[j]); wave w handles o = 5w..5w+4
    #pragma unroll
    for (int oo = 0; oo < 5; ++oo) {
        const int o = wave * 5 + oo;
        const float* ocp = oc + o * (ND * ND) + lane * ND;  // row i = lane
        float acc = 0.f;
        #pragma unroll
        for (int j = 0; j < ND; j += 4) {
            const float4 r4 = *(const float4*)(rbuf + j);
            const float4 c4 = *(const float4*)(ocp + j);
            acc = fmaf(c4.x, r4.x, acc);
            acc = fmaf(c4.y, r4.y, acc);
            acc = fmaf(c4.z, r4.z, acc);
            acc = fmaf(c4.w, r4.w, acc);
        }
        float p = lbuf[lane] * acc;
        #pragma unroll
        for (int off = 32; off > 0; off >>= 1) p += __shfl_xor(p, off, 64);
        if (lane == 0) out[b * NO + o] = p;
    }
}
} // namespace

extern "C" void kernel_launch(void* const* d_in, const int* in_sizes, int n_in,
                              void* d_out, int out_size, void* d_ws, size_t ws_size,
                              hipStream_t stream) {
    const float* x     = (const float*)d_in[0];
    const float* cores = (const float*)d_in[1];
    const float* ocp   = (const float*)d_in[2];
    float* out = (float*)d_out;
    hipLaunchKernelGGL(mps_kernel, dim3(NB), dim3(128), 0, stream, x, cores, ocp, out);
}

// Round 2
// 147.671 us; speedup vs baseline: 2.6952x; 2.6952x over previous
//
#include <hip/hip_runtime.h>

namespace {
constexpr int NB = 64;    // batches
constexpr int NS = 196;   // sites
constexpr int ND = 64;    // bond dim
constexpr int HALF = 98;  // sites per chain (even)
constexpr int NO = 10;

// Layouts:
//   x     [B][S][2]
//   cores [S][D][D][2]   (site, l, r, core-index)  row stride = 128 floats
//   oc    [O][D][D]
//
// left chain  (wave 0): v'[r] = x0*sum_l v[l]*c0[l,r] + x1*sum_l v[l]*c1[l,r]
//   lane = r: loads 64 float2 at stride 512B (coalesced across lanes per l)
// right chain (wave 1): w'[l] = x0*sum_r c0[l,r]*w[r] + x1*sum_r c1[l,r]*w[r]
//   lane = l: loads one contiguous 512B row (32 float4)

#define LPREF(BUF, S)                                                        \
  { const float* _p = cL + (size_t)(S) * 8192;                               \
    _Pragma("unroll") for (int l = 0; l < 64; ++l)                           \
      BUF[l] = *(const float2*)(_p + l * 128); }

#define LCOMP(BUF, XC, VOUT)                                                 \
  { float a0 = 0.f, a1 = 0.f, b0 = 0.f, b1 = 0.f;                            \
    _Pragma("unroll") for (int l = 0; l < 64; l += 4) {                      \
      const float4 v4 = *(const float4*)(lbuf + l);                          \
      a0 = fmaf(v4.x, BUF[l    ].x, a0); b0 = fmaf(v4.x, BUF[l    ].y, b0);  \
      a1 = fmaf(v4.y, BUF[l + 1].x, a1); b1 = fmaf(v4.y, BUF[l + 1].y, b1);  \
      a0 = fmaf(v4.z, BUF[l + 2].x, a0); b0 = fmaf(v4.z, BUF[l + 2].y, b0);  \
      a1 = fmaf(v4.w, BUF[l + 3].x, a1); b1 = fmaf(v4.w, BUF[l + 3].y, b1);  \
    }                                                                        \
    VOUT = (XC).x * (a0 + a1) + (XC).y * (b0 + b1); }

#define RPREF(BUF, S)                                                        \
  { const float4* _p = (const float4*)(cR + (size_t)(S) * 8192);             \
    _Pragma("unroll") for (int j = 0; j < 32; ++j) BUF[j] = _p[j]; }

#define RCOMP(BUF, XC, VOUT)                                                 \
  { float a0 = 0.f, a1 = 0.f, b0 = 0.f, b1 = 0.f;                            \
    _Pragma("unroll") for (int r = 0; r < 64; r += 4) {                      \
      const float4 w4 = *(const float4*)(rbuf + r);                          \
      const float4 q0 = BUF[r / 2], q1 = BUF[r / 2 + 1];                     \
      a0 = fmaf(w4.x, q0.x, a0); b0 = fmaf(w4.x, q0.y, b0);                  \
      a1 = fmaf(w4.y, q0.z, a1); b1 = fmaf(w4.y, q0.w, b1);                  \
      a0 = fmaf(w4.z, q1.x, a0); b0 = fmaf(w4.z, q1.y, b0);                  \
      a1 = fmaf(w4.w, q1.z, a1); b1 = fmaf(w4.w, q1.w, b1);                  \
    }                                                                        \
    VOUT = (XC).x * (a0 + a1) + (XC).y * (b0 + b1); }

__global__ __launch_bounds__(128, 1) void mps_kernel(
    const float* __restrict__ x,      // [B][S][2]
    const float* __restrict__ cores,  // [S][D][D][2]
    const float* __restrict__ oc,     // [O][D][D]
    float* __restrict__ out)          // [B][O]
{
    __shared__ __align__(16) float lbuf[ND];
    __shared__ __align__(16) float rbuf[ND];

    const int b    = blockIdx.x;
    const int tid  = threadIdx.x;
    const int wave = tid >> 6;   // 0 = left chain, 1 = right chain
    const int lane = tid & 63;
    const float2* xp = (const float2*)(x + b * (NS * 2));  // xp[s] = (x0,x1)

    if (wave == 0) {
        // ---- left chain: steps 0..97, row-vector propagation ----
        const float* cL = cores + lane * 2;   // column r = lane
        float2 A[64], Bv[64];
        lbuf[lane] = (lane == 0) ? 1.0f : 0.0f;
        LPREF(A, 0);
        float2 xc = xp[0];
        for (int s = 0; s < HALF; s += 2) {
            LPREF(Bv, s + 1);
            float2 xn = xp[s + 1];
            const int s2 = (s + 2 < HALF) ? s + 2 : HALF - 1;  // clamp (dead prefetch on last iter)
            float vn;
            LCOMP(A, xc, vn);
            lbuf[lane] = vn;                  // in-wave lockstep, LDS in-order
            LPREF(A, s2);
            float2 x2 = xp[s2];
            LCOMP(Bv, xn, vn);
            lbuf[lane] = vn;
            xc = x2;
        }
    } else {
        // ---- right chain: steps 195..98, column-vector propagation ----
        const float* cR = cores + lane * 128;  // row l = lane (contiguous)
        float4 A[32], Bv[32];
        rbuf[lane] = (lane == 0) ? 1.0f : 0.0f;
        RPREF(A, NS - 1);
        float2 xc = xp[NS - 1];
        for (int k = 0; k < HALF; k += 2) {
            const int s1 = NS - 2 - k;                               // second step this iter
            const int s2 = (k + 2 < HALF) ? NS - 3 - k : HALF;       // clamp
            RPREF(Bv, s1);
            float2 xn = xp[s1];
            float wn;
            RCOMP(A, xc, wn);
            rbuf[lane] = wn;
            RPREF(A, s2);
            float2 x2 = xp[s2];
            RCOMP(Bv, xn, wn);
            rbuf[lane] = wn;
            xc = x2;
        }
    }
    __syncthreads();

    // out[b,o] = sum_i lvec[i] * (sum_j oc[o,i,j] * rvec[j]); wave w -> o = 5w..5w+4
    #pragma unroll
    for (int oo = 0; oo < 5; ++oo) {
        const int o = wave * 5 + oo;
        const float* ocp = oc + o * (ND * ND) + lane * ND;  // row i = lane
        float acc = 0.f;
        #pragma unroll
        for (int j = 0; j < ND; j += 4) {
            const float4 r4 = *(const float4*)(rbuf + j);
            const float4 c4 = *(const float4*)(ocp + j);
            acc = fmaf(c4.x, r4.x, acc);
            acc = fmaf(c4.y, r4.y, acc);
            acc = fmaf(c4.z, r4.z, acc);
            acc = fmaf(c4.w, r4.w, acc);
        }
        float p = lbuf[lane] * acc;
        #pragma unroll
        for (int off = 32; off > 0; off >>= 1) p += __shfl_xor(p, off, 64);
        if (lane == 0) out[b * NO + o] = p;
    }
}
} // namespace

extern "C" void kernel_launch(void* const* d_in, const int* in_sizes, int n_in,
                              void* d_out, int out_size, void* d_ws, size_t ws_size,
                              hipStream_t stream) {
    const float* x     = (const float*)d_in[0];
    const float* cores = (const float*)d_in[1];
    const float* ocp   = (const float*)d_in[2];
    float* out = (float*)d_out;
    hipLaunchKernelGGL(mps_kernel, dim3(NB), dim3(128), 0, stream, x, cores, ocp, out);
}

// Round 3
// 136.281 us; speedup vs baseline: 2.9204x; 1.0836x over previous
//
#include <hip/hip_runtime.h>

namespace {
constexpr int NB = 64;    // batches
constexpr int NS = 196;   // sites
constexpr int ND = 64;    // bond dim
constexpr int HALF = 98;  // sites per chain (even)
constexpr int NO = 10;

// Layouts:
//   x     [B][S][2]        cores [S][D][D][2] (row stride 128 floats)   oc [O][D][D]
//
// Left chain (wave 0): v'[r] = x0*sum_l v[l]*c0[l,r] + x1*sum_l v[l]*c1[l,r]
//   lane = h*32+j owns columns r0=2j, r1=2j+1 over l in [h*32, h*32+32).
//   Per step: 32 float4 loads (16B, stride 512B), 128 FMA, 2 shfl_xor(32) to merge halves.
// Right chain (wave 1): w'[l] = x0*sum_r c0[l,r]*w[r] + x1*sum_r c1[l,r]*w[r]
//   lane = l reads its contiguous 512B row: 32 float4 loads, 128 FMA.
//
// sched_barrier(0) after every prefetch block pins the double-buffer: loads for
// step s+1 must ISSUE before compute of step s (compiler cannot sink them).

#define SB() __builtin_amdgcn_sched_barrier(0)

#define LPREF(BUF, S)                                                         \
  { const float* _p = cores + (size_t)(S) * 8192 + lbase * 128 + j * 4;       \
    _Pragma("unroll") for (int i = 0; i < 32; ++i)                            \
      BUF[i] = *(const float4*)(_p + i * 128); }

#define LCOMP(BUF, X0, X1)                                                    \
  { float ax = 0.f, ay = 0.f, az = 0.f, aw = 0.f;                             \
    _Pragma("unroll") for (int i = 0; i < 32; i += 4) {                       \
      const float4 v4 = *(const float4*)(lbuf + lbase + i);                   \
      ax = fmaf(v4.x, BUF[i  ].x, ax); ay = fmaf(v4.x, BUF[i  ].y, ay);       \
      az = fmaf(v4.x, BUF[i  ].z, az); aw = fmaf(v4.x, BUF[i  ].w, aw);       \
      ax = fmaf(v4.y, BUF[i+1].x, ax); ay = fmaf(v4.y, BUF[i+1].y, ay);       \
      az = fmaf(v4.y, BUF[i+1].z, az); aw = fmaf(v4.y, BUF[i+1].w, aw);       \
      ax = fmaf(v4.z, BUF[i+2].x, ax); ay = fmaf(v4.z, BUF[i+2].y, ay);       \
      az = fmaf(v4.z, BUF[i+2].z, az); aw = fmaf(v4.z, BUF[i+2].w, aw);       \
      ax = fmaf(v4.w, BUF[i+3].x, ax); ay = fmaf(v4.w, BUF[i+3].y, ay);       \
      az = fmaf(v4.w, BUF[i+3].z, az); aw = fmaf(v4.w, BUF[i+3].w, aw);       \
    }                                                                         \
    float y0 = fmaf(X0, ax, (X1) * ay);                                       \
    float y1 = fmaf(X0, az, (X1) * aw);                                       \
    y0 += __shfl_xor(y0, 32, 64);                                             \
    y1 += __shfl_xor(y1, 32, 64);                                             \
    if (h == 0) *(float2*)(lbuf + 2 * j) = make_float2(y0, y1); }

#define RPREF(BUF, S)                                                         \
  { const float4* _p = (const float4*)(cores + (size_t)(S) * 8192 + lane * 128); \
    _Pragma("unroll") for (int i = 0; i < 32; ++i) BUF[i] = _p[i]; }

#define RCOMP(BUF, X0, X1)                                                    \
  { float a0 = 0.f, b0 = 0.f, a1 = 0.f, b1 = 0.f;                             \
    _Pragma("unroll") for (int i = 0; i < 32; i += 2) {                       \
      const float4 w4 = *(const float4*)(rbuf + 2 * i);                       \
      const float4 q0 = BUF[i], q1 = BUF[i + 1];                              \
      a0 = fmaf(w4.x, q0.x, a0); b0 = fmaf(w4.x, q0.y, b0);                   \
      a1 = fmaf(w4.y, q0.z, a1); b1 = fmaf(w4.y, q0.w, b1);                   \
      a0 = fmaf(w4.z, q1.x, a0); b0 = fmaf(w4.z, q1.y, b0);                   \
      a1 = fmaf(w4.w, q1.z, a1); b1 = fmaf(w4.w, q1.w, b1);                   \
    }                                                                         \
    rbuf[lane] = fmaf(X0, a0 + a1, (X1) * (b0 + b1)); }

__global__ __launch_bounds__(128, 1) void mps_kernel(
    const float* __restrict__ x,      // [B][S][2]
    const float* __restrict__ cores,  // [S][D][D][2]
    const float* __restrict__ oc,     // [O][D][D]
    float* __restrict__ out)          // [B][O]
{
    __shared__ __align__(16) float lbuf[ND];
    __shared__ __align__(16) float rbuf[ND];

    const int b    = blockIdx.x;
    const int tid  = threadIdx.x;
    const int wave = tid >> 6;
    const int lane = tid & 63;
    const float* xb = x + b * (NS * 2);

    if (wave == 0) {
        const int h = lane >> 5, j = lane & 31;
        const int lbase = h * 32;
        float4 A[32], Bv[32];
        lbuf[lane] = (lane == 0) ? 1.0f : 0.0f;
        LPREF(A, 0);
        float4 xa = *(const float4*)(xb);            // steps 0,1
        for (int s = 0; s < 96; s += 2) {
            LPREF(Bv, s + 1);
            const float4 xn = *(const float4*)(xb + 2 * (s + 2));  // steps s+2,s+3
            SB();
            LCOMP(A, xa.x, xa.y);                    // step s
            LPREF(A, s + 2);
            SB();
            LCOMP(Bv, xa.z, xa.w);                   // step s+1
            xa = xn;
        }
        LPREF(Bv, 97);
        SB();
        LCOMP(A, xa.x, xa.y);                        // step 96
        SB();
        LCOMP(Bv, xa.z, xa.w);                       // step 97
    } else {
        float4 A[32], Bv[32];
        rbuf[lane] = (lane == 0) ? 1.0f : 0.0f;
        RPREF(A, NS - 1);
        float4 xa = *(const float4*)(xb + 2 * 194);  // steps 194,195
        for (int k = 0; k < 96; k += 2) {
            RPREF(Bv, 194 - k);
            const float4 xn = *(const float4*)(xb + 2 * (192 - k));  // steps 192-k,193-k
            SB();
            RCOMP(A, xa.z, xa.w);                    // step 195-k
            RPREF(A, 193 - k);
            SB();
            RCOMP(Bv, xa.x, xa.y);                   // step 194-k
            xa = xn;
        }
        RPREF(Bv, 98);
        SB();
        RCOMP(A, xa.z, xa.w);                        // step 99
        SB();
        RCOMP(Bv, xa.x, xa.y);                       // step 98
    }
    __syncthreads();

    // out[b,o] = sum_i lvec[i] * (sum_j oc[o,i,j] * rvec[j]); wave w -> o = 5w..5w+4
    #pragma unroll
    for (int oo = 0; oo < 5; ++oo) {
        const int o = wave * 5 + oo;
        const float* ocp = oc + o * (ND * ND) + lane * ND;
        float acc = 0.f;
        #pragma unroll
        for (int t = 0; t < ND; t += 4) {
            const float4 r4 = *(const float4*)(rbuf + t);
            const float4 c4 = *(const float4*)(ocp + t);
            acc = fmaf(c4.x, r4.x, acc);
            acc = fmaf(c4.y, r4.y, acc);
            acc = fmaf(c4.z, r4.z, acc);
            acc = fmaf(c4.w, r4.w, acc);
        }
        float p = lbuf[lane] * acc;
        #pragma unroll
        for (int off = 32; off > 0; off >>= 1) p += __shfl_xor(p, off, 64);
        if (lane == 0) out[b * NO + o] = p;
    }
}
} // namespace

extern "C" void kernel_launch(void* const* d_in, const int* in_sizes, int n_in,
                              void* d_out, int out_size, void* d_ws, size_t ws_size,
                              hipStream_t stream) {
    const float* x     = (const float*)d_in[0];
    const float* cores = (const float*)d_in[1];
    const float* ocp   = (const float*)d_in[2];
    float* out = (float*)d_out;
    hipLaunchKernelGGL(mps_kernel, dim3(NB), dim3(128), 0, stream, x, cores, ocp, out);
}

// Round 6
// 129.216 us; speedup vs baseline: 3.0801x; 1.0547x over previous
//
#include <hip/hip_runtime.h>

namespace {
constexpr int NB = 64;    // batches
constexpr int NS = 196;   // sites
constexpr int ND = 64;    // bond dim
constexpr int NO = 10;

// Layouts: x [B][S][2] ; cores [S][D][D][2] (site 32768B, row 512B) ; oc [O][D][D]
//
// Per block (batch b): wave0 = left chain (sites 0..97, row-vector e0^T·prod),
// wave1 = right chain (sites 195..98, col-vector prod·e0).
// Each wave: depth-2 LDS pipeline. Site tile (32KB) staged by 32x
// global_load_lds dwordx4 (64 lanes x 16B = 1KB per instr). Counted
// s_waitcnt vmcnt(32) = "oldest site's 32 loads landed, newer 32 in flight".
// lgkmcnt(0) before re-staging a buffer guarantees its ds_reads retired.
// Async dst = LDS (not VGPRs): mis-timing can only give stale data, no fault.
//
// Right tile is XOR-swizzled (slot ^= (row&7)) to kill the stride-512B read
// conflict; global_load_lds writes linearly, so the swizzle is applied by
// permuting the per-lane GLOBAL source address (rule #21), which keeps loads
// coalesced (permutation within each 512B block).

typedef const __attribute__((address_space(1))) void* gasp_t;
typedef __attribute__((address_space(3))) void* lasp_t;

#define SB0() __builtin_amdgcn_sched_barrier(0)
#define WAITV(N) do { asm volatile("s_waitcnt vmcnt(" #N ")" ::: "memory"); SB0(); } while (0)
#define LGKM0() do { asm volatile("s_waitcnt lgkmcnt(0)" ::: "memory"); SB0(); } while (0)
#define GL2LDS(g, l) __builtin_amdgcn_global_load_lds((gasp_t)(g), (lasp_t)(l), 16, 0, 0)

// ---- left wave: stage site S (linear layout) into tile T ----
#define LISSUE(T, S) do {                                                     \
  const float* _g = cores + (size_t)(S) * 8192 + lane * 4;                    \
  _Pragma("unroll") for (int i = 0; i < 32; ++i)                              \
    GL2LDS(_g + i * 256, (T) + i * 256);                                      \
} while (0)

// ---- right wave: stage site S swizzled (source pre-permuted) ----
#define RISSUE(T, S) do {                                                     \
  const float* _g = cores + (size_t)(S) * 8192;                               \
  _Pragma("unroll") for (int k = 0; k < 32; ++k)                              \
    GL2LDS(_g + k * 256 + roff[k & 3], (T) + k * 256);                        \
} while (0)

// ---- left compute: lane (h,j) -> columns 2j,2j+1, rows 32h..32h+31 ----
#define LCOMP(TILE, X0, X1) do {                                              \
  const float4* _t = (const float4*)(TILE) + (h << 10) + j;                   \
  float ax = 0.f, ay = 0.f, az = 0.f, aw = 0.f;                               \
  _Pragma("unroll") for (int i = 0; i < 32; i += 4) {                         \
    const float4 v4 = *(const float4*)(lbuf + (h << 5) + i);                  \
    const float4 t0 = _t[(i + 0) << 5];                                       \
    const float4 t1 = _t[(i + 1) << 5];                                       \
    const float4 t2 = _t[(i + 2) << 5];                                       \
    const float4 t3 = _t[(i + 3) << 5];                                       \
    ax = fmaf(v4.x, t0.x, ax); ay = fmaf(v4.x, t0.y, ay);                     \
    az = fmaf(v4.x, t0.z, az); aw = fmaf(v4.x, t0.w, aw);                     \
    ax = fmaf(v4.y, t1.x, ax); ay = fmaf(v4.y, t1.y, ay);                     \
    az = fmaf(v4.y, t1.z, az); aw = fmaf(v4.y, t1.w, aw);                     \
    ax = fmaf(v4.z, t2.x, ax); ay = fmaf(v4.z, t2.y, ay);                     \
    az = fmaf(v4.z, t2.z, az); aw = fmaf(v4.z, t2.w, aw);                     \
    ax = fmaf(v4.w, t3.x, ax); ay = fmaf(v4.w, t3.y, ay);                     \
    az = fmaf(v4.w, t3.z, az); aw = fmaf(v4.w, t3.w, aw);                     \
  }                                                                           \
  float y0 = fmaf((X0), ax, (X1) * ay);                                       \
  float y1 = fmaf((X0), az, (X1) * aw);                                       \
  y0 += __shfl_xor(y0, 32, 64);                                               \
  y1 += __shfl_xor(y1, 32, 64);                                               \
  if (h == 0) *(float2*)(lbuf + 2 * j) = make_float2(y0, y1);                 \
} while (0)

// ---- right compute: lane = row l; swizzled granule reads ----
#define RCOMP(TILE, X0, X1) do {                                              \
  const float4* _t = (const float4*)(TILE) + (lane << 5);                     \
  float a0 = 0.f, b0 = 0.f, a1 = 0.f, b1 = 0.f;                               \
  _Pragma("unroll") for (int i = 0; i < 32; i += 2) {                         \
    const float4 w4 = *(const float4*)(rbuf + 2 * i);                         \
    const float4 q0 = _t[(((i + 0) & 7) ^ p7) + (((i + 0) >> 3) << 3)];       \
    const float4 q1 = _t[(((i + 1) & 7) ^ p7) + (((i + 1) >> 3) << 3)];       \
    a0 = fmaf(w4.x, q0.x, a0); b0 = fmaf(w4.x, q0.y, b0);                     \
    a1 = fmaf(w4.y, q0.z, a1); b1 = fmaf(w4.y, q0.w, b1);                     \
    a0 = fmaf(w4.z, q1.x, a0); b0 = fmaf(w4.z, q1.y, b0);                     \
    a1 = fmaf(w4.w, q1.z, a1); b1 = fmaf(w4.w, q1.w, b1);                     \
  }                                                                           \
  rbuf[lane] = fmaf((X0), a0 + a1, (X1) * (b0 + b1));                         \
} while (0)

__global__ __launch_bounds__(128, 1) void mps_kernel(
    const float* __restrict__ x,      // [B][S][2]
    const float* __restrict__ cores,  // [S][D][D][2]
    const float* __restrict__ oc,     // [O][D][D]
    float* __restrict__ out)          // [B][O]
{
    __shared__ __align__(16) float ltile[2][8192];
    __shared__ __align__(16) float rtile[2][8192];
    __shared__ __align__(16) float lbuf[ND];
    __shared__ __align__(16) float rbuf[ND];

    const int b    = blockIdx.x;
    const int tid  = threadIdx.x;
    const int wave = tid >> 6;
    const int lane = tid & 63;
    const float* xb = x + b * (NS * 2);   // wave-uniform reads -> s_load (lgkmcnt)

    if (wave == 0) {
        const int h = lane >> 5, j = lane & 31;
        lbuf[lane] = (lane == 0) ? 1.0f : 0.0f;
        LISSUE(ltile[0], 0);
        LISSUE(ltile[1], 1);
        for (int s = 0; s < 96; s += 2) {
            const float2 xa = *(const float2*)(xb + 2 * s);
            const float2 xn = *(const float2*)(xb + 2 * s + 2);
            WAITV(32); LCOMP(ltile[0], xa.x, xa.y); LGKM0(); LISSUE(ltile[0], s + 2);
            WAITV(32); LCOMP(ltile[1], xn.x, xn.y); LGKM0(); LISSUE(ltile[1], s + 3);
        }
        {
            const float2 xa = *(const float2*)(xb + 192);   // site 96
            const float2 xn = *(const float2*)(xb + 194);   // site 97
            WAITV(32); LCOMP(ltile[0], xa.x, xa.y);
            WAITV(0);  LCOMP(ltile[1], xn.x, xn.y);         // fully drained
        }
    } else {
        const int p7 = lane & 7;
        const int h2 = lane >> 5, j2 = lane & 31;
        int roff[4];
        #pragma unroll
        for (int m4 = 0; m4 < 4; ++m4)
            roff[m4] = h2 * 128 + ((j2 >> 3) << 5) + (((j2 & 7) ^ (2 * m4 + h2)) << 2);
        rbuf[lane] = (lane == 0) ? 1.0f : 0.0f;
        RISSUE(rtile[0], 195);
        RISSUE(rtile[1], 194);
        for (int k = 0; k < 96; k += 2) {
            const float2 xa = *(const float2*)(xb + 2 * (195 - k));
            const float2 xn = *(const float2*)(xb + 2 * (194 - k));
            WAITV(32); RCOMP(rtile[0], xa.x, xa.y); LGKM0(); RISSUE(rtile[0], 193 - k);
            WAITV(32); RCOMP(rtile[1], xn.x, xn.y); LGKM0(); RISSUE(rtile[1], 192 - k);
        }
        {
            const float2 xa = *(const float2*)(xb + 2 * 99);  // site 99
            const float2 xn = *(const float2*)(xb + 2 * 98);  // site 98
            WAITV(32); RCOMP(rtile[0], xa.x, xa.y);
            WAITV(0);  RCOMP(rtile[1], xn.x, xn.y);           // fully drained
        }
    }
    __syncthreads();

    // out[b,o] = sum_i lvec[i] * (sum_j oc[o,i,j] * rvec[j]); wave w -> o = 5w..5w+4
    #pragma unroll
    for (int oo = 0; oo < 5; ++oo) {
        const int o = wave * 5 + oo;
        const float* ocp = oc + o * (ND * ND) + lane * ND;
        float acc = 0.f;
        #pragma unroll
        for (int t = 0; t < ND; t += 4) {
            const float4 r4 = *(const float4*)(rbuf + t);
            const float4 c4 = *(const float4*)(ocp + t);
            acc = fmaf(c4.x, r4.x, acc);
            acc = fmaf(c4.y, r4.y, acc);
            acc = fmaf(c4.z, r4.z, acc);
            acc = fmaf(c4.w, r4.w, acc);
        }
        float p = lbuf[lane] * acc;
        #pragma unroll
        for (int off = 32; off > 0; off >>= 1) p += __shfl_xor(p, off, 64);
        if (lane == 0) out[b * NO + o] = p;
    }
}
} // namespace

extern "C" void kernel_launch(void* const* d_in, const int* in_sizes, int n_in,
                              void* d_out, int out_size, void* d_ws, size_t ws_size,
                              hipStream_t stream) {
    const float* x     = (const float*)d_in[0];
    const float* cores = (const float*)d_in[1];
    const float* ocp   = (const float*)d_in[2];
    float* out = (float*)d_out;
    hipLaunchKernelGGL(mps_kernel, dim3(NB), dim3(128), 0, stream, x, cores, ocp, out);
}

// Round 7
// 114.650 us; speedup vs baseline: 3.4715x; 1.1270x over previous
//
#include <hip/hip_runtime.h>

namespace {
constexpr int NB = 64;    // batches
constexpr int NS = 196;   // sites
constexpr int ND = 64;    // bond dim
constexpr int NO = 10;

// Layouts: x [B][S][2] ; cores [S][D][D][2] (site 32768B, row 512B) ; oc [O][D][D]
//
// wave0 = left chain (sites 0..97, e0^T·prod), wave1 = right chain (195..98, prod·e0).
// Depth-2 LDS pipeline per wave: site tile (32KB) staged by 32x global_load_lds dwordx4.
// Counted s_waitcnt vmcnt(32) = oldest tile landed, newer 32 in flight. lgkmcnt(0)
// before re-staging a consumed tile. Async dst = LDS: mis-timing => stale data, no fault.
// CRITICAL (R7): x[b] is staged into LDS in the prologue. The main loop has NO
// compiler-issued VMEM ops, so the compiler never inserts its own vmcnt waits
// (it can't count our asm loads and would conservatively drain the pipeline).
//
// Right tile XOR-swizzled via pre-permuted global source (rule #21) to spread the
// stride-512B row reads across banks; left tile reads are naturally contiguous.

typedef const __attribute__((address_space(1))) void* gasp_t;
typedef __attribute__((address_space(3))) void* lasp_t;

#define SB0() __builtin_amdgcn_sched_barrier(0)
#define WAITV(N) do { asm volatile("s_waitcnt vmcnt(" #N ")" ::: "memory"); SB0(); } while (0)
#define LGKM0() do { asm volatile("s_waitcnt lgkmcnt(0)" ::: "memory"); SB0(); } while (0)
#define GL2LDS(g, l) __builtin_amdgcn_global_load_lds((gasp_t)(g), (lasp_t)(l), 16, 0, 0)

// ---- left wave: stage site S (linear) into tile T ----
#define LISSUE(T, S) do {                                                     \
  const float* _g = cores + (size_t)(S) * 8192 + lane * 4;                    \
  _Pragma("unroll") for (int i = 0; i < 32; ++i)                              \
    GL2LDS(_g + i * 256, (T) + i * 256);                                      \
} while (0)

// ---- right wave: stage site S swizzled (source pre-permuted) ----
#define RISSUE(T, S) do {                                                     \
  const float* _g = cores + (size_t)(S) * 8192;                               \
  _Pragma("unroll") for (int k = 0; k < 32; ++k)                              \
    GL2LDS(_g + k * 256 + roff[k & 3], (T) + k * 256);                        \
} while (0)

// ---- left compute: lane (h,j) -> columns 2j,2j+1, rows 32h..32h+31 ----
// 8 accumulators: dep chain 16 FMAs per accumulator.
#define LCOMP(TILE, X0, X1) do {                                              \
  const float4* _t = (const float4*)(TILE) + (h << 10) + j;                   \
  float ax0=0.f, ay0=0.f, az0=0.f, aw0=0.f;                                   \
  float ax1=0.f, ay1=0.f, az1=0.f, aw1=0.f;                                   \
  _Pragma("unroll") for (int i = 0; i < 32; i += 8) {                         \
    const float4 va = *(const float4*)(lbuf + (h << 5) + i);                  \
    const float4 vb = *(const float4*)(lbuf + (h << 5) + i + 4);              \
    const float4 t0 = _t[(i + 0) << 5];                                       \
    const float4 t1 = _t[(i + 1) << 5];                                       \
    const float4 t2 = _t[(i + 2) << 5];                                       \
    const float4 t3 = _t[(i + 3) << 5];                                       \
    const float4 t4 = _t[(i + 4) << 5];                                       \
    const float4 t5 = _t[(i + 5) << 5];                                       \
    const float4 t6 = _t[(i + 6) << 5];                                       \
    const float4 t7 = _t[(i + 7) << 5];                                       \
    ax0 = fmaf(va.x, t0.x, ax0); ay0 = fmaf(va.x, t0.y, ay0);                 \
    az0 = fmaf(va.x, t0.z, az0); aw0 = fmaf(va.x, t0.w, aw0);                 \
    ax0 = fmaf(va.y, t1.x, ax0); ay0 = fmaf(va.y, t1.y, ay0);                 \
    az0 = fmaf(va.y, t1.z, az0); aw0 = fmaf(va.y, t1.w, aw0);                 \
    ax0 = fmaf(va.z, t2.x, ax0); ay0 = fmaf(va.z, t2.y, ay0);                 \
    az0 = fmaf(va.z, t2.z, az0); aw0 = fmaf(va.z, t2.w, aw0);                 \
    ax0 = fmaf(va.w, t3.x, ax0); ay0 = fmaf(va.w, t3.y, ay0);                 \
    az0 = fmaf(va.w, t3.z, az0); aw0 = fmaf(va.w, t3.w, aw0);                 \
    ax1 = fmaf(vb.x, t4.x, ax1); ay1 = fmaf(vb.x, t4.y, ay1);                 \
    az1 = fmaf(vb.x, t4.z, az1); aw1 = fmaf(vb.x, t4.w, aw1);                 \
    ax1 = fmaf(vb.y, t5.x, ax1); ay1 = fmaf(vb.y, t5.y, ay1);                 \
    az1 = fmaf(vb.y, t5.z, az1); aw1 = fmaf(vb.y, t5.w, aw1);                 \
    ax1 = fmaf(vb.z, t6.x, ax1); ay1 = fmaf(vb.z, t6.y, ay1);                 \
    az1 = fmaf(vb.z, t6.z, az1); aw1 = fmaf(vb.z, t6.w, aw1);                 \
    ax1 = fmaf(vb.w, t7.x, ax1); ay1 = fmaf(vb.w, t7.y, ay1);                 \
    az1 = fmaf(vb.w, t7.z, az1); aw1 = fmaf(vb.w, t7.w, aw1);                 \
  }                                                                           \
  float y0 = fmaf((X0), ax0 + ax1, (X1) * (ay0 + ay1));                       \
  float y1 = fmaf((X0), az0 + az1, (X1) * (aw0 + aw1));                       \
  y0 += __shfl_xor(y0, 32, 64);                                               \
  y1 += __shfl_xor(y1, 32, 64);                                               \
  if (h == 0) *(float2*)(lbuf + 2 * j) = make_float2(y0, y1);                 \
} while (0)

// ---- right compute: lane = row l; swizzled granule reads; 8 accumulators ----
#define RCOMP(TILE, X0, X1) do {                                              \
  const float4* _t = (const float4*)(TILE) + (lane << 5);                     \
  float a0=0.f, b0=0.f, a1=0.f, b1=0.f, a2=0.f, b2=0.f, a3=0.f, b3=0.f;       \
  _Pragma("unroll") for (int i = 0; i < 32; i += 4) {                         \
    const float4 wa = *(const float4*)(rbuf + 2 * i);                         \
    const float4 wb = *(const float4*)(rbuf + 2 * i + 4);                     \
    const float4 q0 = _t[(((i + 0) & 7) ^ p7) + (((i + 0) >> 3) << 3)];       \
    const float4 q1 = _t[(((i + 1) & 7) ^ p7) + (((i + 1) >> 3) << 3)];       \
    const float4 q2 = _t[(((i + 2) & 7) ^ p7) + (((i + 2) >> 3) << 3)];       \
    const float4 q3 = _t[(((i + 3) & 7) ^ p7) + (((i + 3) >> 3) << 3)];       \
    a0 = fmaf(wa.x, q0.x, a0); b0 = fmaf(wa.x, q0.y, b0);                     \
    a1 = fmaf(wa.y, q0.z, a1); b1 = fmaf(wa.y, q0.w, b1);                     \
    a0 = fmaf(wa.z, q1.x, a0); b0 = fmaf(wa.z, q1.y, b0);                     \
    a1 = fmaf(wa.w, q1.z, a1); b1 = fmaf(wa.w, q1.w, b1);                     \
    a2 = fmaf(wb.x, q2.x, a2); b2 = fmaf(wb.x, q2.y, b2);                     \
    a3 = fmaf(wb.y, q2.z, a3); b3 = fmaf(wb.y, q2.w, b3);                     \
    a2 = fmaf(wb.z, q3.x, a2); b2 = fmaf(wb.z, q3.y, b2);                     \
    a3 = fmaf(wb.w, q3.z, a3); b3 = fmaf(wb.w, q3.w, b3);                     \
  }                                                                           \
  rbuf[lane] = fmaf((X0), (a0 + a1) + (a2 + a3),                              \
                    (X1) * ((b0 + b1) + (b2 + b3)));                          \
} while (0)

__global__ __launch_bounds__(128, 1) void mps_kernel(
    const float* __restrict__ x,      // [B][S][2]
    const float* __restrict__ cores,  // [S][D][D][2]
    const float* __restrict__ oc,     // [O][D][D]
    float* __restrict__ out)          // [B][O]
{
    __shared__ __align__(16) float ltile[2][8192];
    __shared__ __align__(16) float rtile[2][8192];
    __shared__ __align__(16) float lbuf[ND];
    __shared__ __align__(16) float rbuf[ND];
    __shared__ __align__(16) float xlds[NS * 2];

    const int b    = blockIdx.x;
    const int tid  = threadIdx.x;
    const int wave = tid >> 6;
    const int lane = tid & 63;

    // Stage x[b] (392 floats = 98 float4) into LDS: the main loop then contains
    // NO compiler-issued VMEM ops (x reads become ds_read -> lgkmcnt only).
    if (tid < 98) ((float4*)xlds)[tid] = ((const float4*)(x + b * (NS * 2)))[tid];
    if (wave == 0) lbuf[lane] = (lane == 0) ? 1.0f : 0.0f;
    else           rbuf[lane] = (lane == 0) ? 1.0f : 0.0f;
    __syncthreads();
    const float2* xp2 = (const float2*)xlds;

    if (wave == 0) {
        const int h = lane >> 5, j = lane & 31;
        LISSUE(ltile[0], 0);
        LISSUE(ltile[1], 1);
        for (int s = 0; s < 96; s += 2) {
            const float2 xa = xp2[s];
            const float2 xn = xp2[s + 1];
            WAITV(32); LCOMP(ltile[0], xa.x, xa.y); LGKM0(); LISSUE(ltile[0], s + 2);
            WAITV(32); LCOMP(ltile[1], xn.x, xn.y); LGKM0(); LISSUE(ltile[1], s + 3);
        }
        {
            const float2 xa = xp2[96];
            const float2 xn = xp2[97];
            WAITV(32); LCOMP(ltile[0], xa.x, xa.y);
            WAITV(0);  LCOMP(ltile[1], xn.x, xn.y);           // fully drained
        }
    } else {
        const int p7 = lane & 7;
        const int h2 = lane >> 5, j2 = lane & 31;
        int roff[4];
        #pragma unroll
        for (int m4 = 0; m4 < 4; ++m4)
            roff[m4] = h2 * 128 + ((j2 >> 3) << 5) + (((j2 & 7) ^ (2 * m4 + h2)) << 2);
        RISSUE(rtile[0], 195);
        RISSUE(rtile[1], 194);
        for (int k = 0; k < 96; k += 2) {
            const float2 xa = xp2[195 - k];
            const float2 xn = xp2[194 - k];
            WAITV(32); RCOMP(rtile[0], xa.x, xa.y); LGKM0(); RISSUE(rtile[0], 193 - k);
            WAITV(32); RCOMP(rtile[1], xn.x, xn.y); LGKM0(); RISSUE(rtile[1], 192 - k);
        }
        {
            const float2 xa = xp2[99];
            const float2 xn = xp2[98];
            WAITV(32); RCOMP(rtile[0], xa.x, xa.y);
            WAITV(0);  RCOMP(rtile[1], xn.x, xn.y);           // fully drained
        }
    }
    __syncthreads();

    // out[b,o] = sum_i lvec[i] * (sum_j oc[o,i,j] * rvec[j]); wave w -> o = 5w..5w+4
    #pragma unroll
    for (int oo = 0; oo < 5; ++oo) {
        const int o = wave * 5 + oo;
        const float* ocp = oc + o * (ND * ND) + lane * ND;
        float acc = 0.f;
        #pragma unroll
        for (int t = 0; t < ND; t += 4) {
            const float4 r4 = *(const float4*)(rbuf + t);
            const float4 c4 = *(const float4*)(ocp + t);
            acc = fmaf(c4.x, r4.x, acc);
            acc = fmaf(c4.y, r4.y, acc);
            acc = fmaf(c4.z, r4.z, acc);
            acc = fmaf(c4.w, r4.w, acc);
        }
        float p = lbuf[lane] * acc;
        #pragma unroll
        for (int off = 32; off > 0; off >>= 1) p += __shfl_xor(p, off, 64);
        if (lane == 0) out[b * NO + o] = p;
    }
}
} // namespace

extern "C" void kernel_launch(void* const* d_in, const int* in_sizes, int n_in,
                              void* d_out, int out_size, void* d_ws, size_t ws_size,
                              hipStream_t stream) {
    const float* x     = (const float*)d_in[0];
    const float* cores = (const float*)d_in[1];
    const float* ocp   = (const float*)d_in[2];
    float* out = (float*)d_out;
    hipLaunchKernelGGL(mps_kernel, dim3(NB), dim3(128), 0, stream, x, cores, ocp, out);
}

// Round 8
// 99.753 us; speedup vs baseline: 3.9899x; 1.1493x over previous
//
#include <hip/hip_runtime.h>

namespace {
constexpr int NB = 64;    // batches
constexpr int NS = 196;   // sites
constexpr int ND = 64;    // bond dim
constexpr int NO = 10;

// Layouts: x [B][S][2] ; cores [S][D][D][2] (site 32768B, row 512B) ; oc [O][D][D]
//
// R8: per-CU-bandwidth fix. 128 single-wave blocks (block 2b = left chain of
// batch b, 2b+1 = right chain). Each block streams 32KB/site (was 64KB/CU/step
// with both chains per block). Depth-3 LDS ring (96KB -> exactly 1 block/CU)
// staged by 32x global_load_lds dwordx4 per site; counted s_waitcnt vmcnt(63)
// (96 outstanding -> waits oldest tile +1 load), never 0 in-loop; drained
// epilogue. Async dst = LDS: mis-timing can only give stale data, no fault.
// lvec/rvec -> d_ws; second tiny kernel does the output contraction.

typedef const __attribute__((address_space(1))) void* gasp_t;
typedef __attribute__((address_space(3))) void* lasp_t;

#define SB0() __builtin_amdgcn_sched_barrier(0)
#define WAITV(N) do { asm volatile("s_waitcnt vmcnt(" #N ")" ::: "memory"); SB0(); } while (0)
#define LGKM0() do { asm volatile("s_waitcnt lgkmcnt(0)" ::: "memory"); SB0(); } while (0)
#define GL2LDS(g, l) __builtin_amdgcn_global_load_lds((gasp_t)(g), (lasp_t)(l), 16, 0, 0)

// ---- left: stage site S (linear) into tile T ----
#define LISSUE(T, S) do {                                                     \
  const float* _g = cores + (size_t)(S) * 8192 + lane * 4;                    \
  _Pragma("unroll") for (int i = 0; i < 32; ++i)                              \
    GL2LDS(_g + i * 256, (T) + i * 256);                                      \
} while (0)

// ---- right: stage site S swizzled (source pre-permuted, rule #21) ----
#define RISSUE(T, S) do {                                                     \
  const float* _g = cores + (size_t)(S) * 8192;                               \
  _Pragma("unroll") for (int k = 0; k < 32; ++k)                              \
    GL2LDS(_g + k * 256 + roff[k & 3], (T) + k * 256);                        \
} while (0)

// ---- left compute: lane (h,j) -> columns 2j,2j+1, rows 32h..32h+31 ----
#define LCOMP(TILE, X0, X1) do {                                              \
  const float4* _t = (const float4*)(TILE) + (h << 10) + j;                   \
  float ax0=0.f, ay0=0.f, az0=0.f, aw0=0.f;                                   \
  float ax1=0.f, ay1=0.f, az1=0.f, aw1=0.f;                                   \
  _Pragma("unroll") for (int i = 0; i < 32; i += 8) {                         \
    const float4 va = *(const float4*)(vbuf + (h << 5) + i);                  \
    const float4 vb = *(const float4*)(vbuf + (h << 5) + i + 4);              \
    const float4 t0 = _t[(i + 0) << 5];                                       \
    const float4 t1 = _t[(i + 1) << 5];                                       \
    const float4 t2 = _t[(i + 2) << 5];                                       \
    const float4 t3 = _t[(i + 3) << 5];                                       \
    const float4 t4 = _t[(i + 4) << 5];                                       \
    const float4 t5 = _t[(i + 5) << 5];                                       \
    const float4 t6 = _t[(i + 6) << 5];                                       \
    const float4 t7 = _t[(i + 7) << 5];                                       \
    ax0 = fmaf(va.x, t0.x, ax0); ay0 = fmaf(va.x, t0.y, ay0);                 \
    az0 = fmaf(va.x, t0.z, az0); aw0 = fmaf(va.x, t0.w, aw0);                 \
    ax0 = fmaf(va.y, t1.x, ax0); ay0 = fmaf(va.y, t1.y, ay0);                 \
    az0 = fmaf(va.y, t1.z, az0); aw0 = fmaf(va.y, t1.w, aw0);                 \
    ax0 = fmaf(va.z, t2.x, ax0); ay0 = fmaf(va.z, t2.y, ay0);                 \
    az0 = fmaf(va.z, t2.z, az0); aw0 = fmaf(va.z, t2.w, aw0);                 \
    ax0 = fmaf(va.w, t3.x, ax0); ay0 = fmaf(va.w, t3.y, ay0);                 \
    az0 = fmaf(va.w, t3.z, az0); aw0 = fmaf(va.w, t3.w, aw0);                 \
    ax1 = fmaf(vb.x, t4.x, ax1); ay1 = fmaf(vb.x, t4.y, ay1);                 \
    az1 = fmaf(vb.x, t4.z, az1); aw1 = fmaf(vb.x, t4.w, aw1);                 \
    ax1 = fmaf(vb.y, t5.x, ax1); ay1 = fmaf(vb.y, t5.y, ay1);                 \
    az1 = fmaf(vb.y, t5.z, az1); aw1 = fmaf(vb.y, t5.w, aw1);                 \
    ax1 = fmaf(vb.z, t6.x, ax1); ay1 = fmaf(vb.z, t6.y, ay1);                 \
    az1 = fmaf(vb.z, t6.z, az1); aw1 = fmaf(vb.z, t6.w, aw1);                 \
    ax1 = fmaf(vb.w, t7.x, ax1); ay1 = fmaf(vb.w, t7.y, ay1);                 \
    az1 = fmaf(vb.w, t7.z, az1); aw1 = fmaf(vb.w, t7.w, aw1);                 \
  }                                                                           \
  float y0 = fmaf((X0), ax0 + ax1, (X1) * (ay0 + ay1));                       \
  float y1 = fmaf((X0), az0 + az1, (X1) * (aw0 + aw1));                       \
  y0 += __shfl_xor(y0, 32, 64);                                               \
  y1 += __shfl_xor(y1, 32, 64);                                               \
  if (h == 0) *(float2*)(vbuf + 2 * j) = make_float2(y0, y1);                 \
} while (0)

// ---- right compute: lane = row l; swizzled granule reads ----
#define RCOMP(TILE, X0, X1) do {                                              \
  const float4* _t = (const float4*)(TILE) + (lane << 5);                     \
  float a0=0.f, b0=0.f, a1=0.f, b1=0.f, a2=0.f, b2=0.f, a3=0.f, b3=0.f;       \
  _Pragma("unroll") for (int i = 0; i < 32; i += 4) {                         \
    const float4 wa = *(const float4*)(vbuf + 2 * i);                         \
    const float4 wb = *(const float4*)(vbuf + 2 * i + 4);                     \
    const float4 q0 = _t[(((i + 0) & 7) ^ p7) + (((i + 0) >> 3) << 3)];       \
    const float4 q1 = _t[(((i + 1) & 7) ^ p7) + (((i + 1) >> 3) << 3)];       \
    const float4 q2 = _t[(((i + 2) & 7) ^ p7) + (((i + 2) >> 3) << 3)];       \
    const float4 q3 = _t[(((i + 3) & 7) ^ p7) + (((i + 3) >> 3) << 3)];       \
    a0 = fmaf(wa.x, q0.x, a0); b0 = fmaf(wa.x, q0.y, b0);                     \
    a1 = fmaf(wa.y, q0.z, a1); b1 = fmaf(wa.y, q0.w, b1);                     \
    a0 = fmaf(wa.z, q1.x, a0); b0 = fmaf(wa.z, q1.y, b0);                     \
    a1 = fmaf(wa.w, q1.z, a1); b1 = fmaf(wa.w, q1.w, b1);                     \
    a2 = fmaf(wb.x, q2.x, a2); b2 = fmaf(wb.x, q2.y, b2);                     \
    a3 = fmaf(wb.y, q2.z, a3); b3 = fmaf(wb.y, q2.w, b3);                     \
    a2 = fmaf(wb.z, q3.x, a2); b2 = fmaf(wb.z, q3.y, b2);                     \
    a3 = fmaf(wb.w, q3.z, a3); b3 = fmaf(wb.w, q3.w, b3);                     \
  }                                                                           \
  vbuf[lane] = fmaf((X0), (a0 + a1) + (a2 + a3),                              \
                    (X1) * ((b0 + b1) + (b2 + b3)));                          \
} while (0)

__global__ __launch_bounds__(64, 1) void mps_chain_kernel(
    const float* __restrict__ x,      // [B][S][2]
    const float* __restrict__ cores,  // [S][D][D][2]
    float* __restrict__ ws)           // [B][2][64] lvec/rvec
{
    __shared__ __align__(16) float tile[3][8192];   // 96KB -> 1 block/CU
    __shared__ __align__(16) float vbuf[ND];
    __shared__ __align__(16) float xlds[NS * 2];

    const int bid   = blockIdx.x;
    const int batch = bid >> 1;
    const int right = bid & 1;
    const int lane  = threadIdx.x;

    // stage x[batch] into LDS: main loop then has ZERO compiler-issued VMEM ops
    #pragma unroll
    for (int i = lane; i < 98; i += 64)
        ((float4*)xlds)[i] = ((const float4*)(x + batch * (NS * 2)))[i];
    vbuf[lane] = (lane == 0) ? 1.0f : 0.0f;
    __syncthreads();   // also drains vmcnt/lgkmcnt before asm pipeline starts
    const float2* xp2 = (const float2*)xlds;

    if (!right) {
        const int h = lane >> 5, j = lane & 31;
        LISSUE(tile[0], 0); LISSUE(tile[1], 1); LISSUE(tile[2], 2);
        for (int s = 0; s < 96; s += 3) {
            const float2 x0 = xp2[s], x1 = xp2[s + 1], x2 = xp2[s + 2];
            WAITV(63); LCOMP(tile[0], x0.x, x0.y); LGKM0(); LISSUE(tile[0], s + 3);
            WAITV(63); LCOMP(tile[1], x1.x, x1.y); LGKM0(); LISSUE(tile[1], (s + 4 < 98) ? s + 4 : 97);
            WAITV(63); LCOMP(tile[2], x2.x, x2.y); LGKM0(); LISSUE(tile[2], (s + 5 < 98) ? s + 5 : 97);
        }
        const float2 x96 = xp2[96], x97 = xp2[97];
        WAITV(63); LCOMP(tile[0], x96.x, x96.y);   // site 96
        WAITV(0);  LCOMP(tile[1], x97.x, x97.y);   // site 97 — fully drained
        ws[batch * 128 + lane] = vbuf[lane];
    } else {
        const int p7 = lane & 7;
        const int h2 = lane >> 5, j2 = lane & 31;
        int roff[4];
        #pragma unroll
        for (int m4 = 0; m4 < 4; ++m4)
            roff[m4] = h2 * 128 + ((j2 >> 3) << 5) + (((j2 & 7) ^ (2 * m4 + h2)) << 2);
        RISSUE(tile[0], 195); RISSUE(tile[1], 194); RISSUE(tile[2], 193);
        for (int k = 0; k < 96; k += 3) {
            const float2 x0 = xp2[195 - k], x1 = xp2[194 - k], x2 = xp2[193 - k];
            WAITV(63); RCOMP(tile[0], x0.x, x0.y); LGKM0(); RISSUE(tile[0], 192 - k);
            WAITV(63); RCOMP(tile[1], x1.x, x1.y); LGKM0(); RISSUE(tile[1], (191 - k > 98) ? 191 - k : 98);
            WAITV(63); RCOMP(tile[2], x2.x, x2.y); LGKM0(); RISSUE(tile[2], (190 - k > 98) ? 190 - k : 98);
        }
        const float2 x99 = xp2[99], x98 = xp2[98];
        WAITV(63); RCOMP(tile[0], x99.x, x99.y);   // site 99
        WAITV(0);  RCOMP(tile[1], x98.x, x98.y);   // site 98 — fully drained
        ws[batch * 128 + 64 + lane] = vbuf[lane];
    }
}

__global__ __launch_bounds__(128) void mps_out_kernel(
    const float* __restrict__ ws,     // [B][2][64]
    const float* __restrict__ oc,     // [O][D][D]
    float* __restrict__ out)          // [B][O]
{
    __shared__ __align__(16) float lsh[ND];
    __shared__ __align__(16) float rsh[ND];
    const int b    = blockIdx.x;
    const int tid  = threadIdx.x;
    const int wave = tid >> 6;
    const int lane = tid & 63;
    if (wave == 0) lsh[lane] = ws[b * 128 + lane];
    else           rsh[lane] = ws[b * 128 + 64 + lane];
    __syncthreads();

    #pragma unroll
    for (int oo = 0; oo < 5; ++oo) {
        const int o = wave * 5 + oo;
        const float* ocp = oc + o * (ND * ND) + lane * ND;
        float acc = 0.f;
        #pragma unroll
        for (int t = 0; t < ND; t += 4) {
            const float4 r4 = *(const float4*)(rsh + t);
            const float4 c4 = *(const float4*)(ocp + t);
            acc = fmaf(c4.x, r4.x, acc);
            acc = fmaf(c4.y, r4.y, acc);
            acc = fmaf(c4.z, r4.z, acc);
            acc = fmaf(c4.w, r4.w, acc);
        }
        float p = lsh[lane] * acc;
        #pragma unroll
        for (int off = 32; off > 0; off >>= 1) p += __shfl_xor(p, off, 64);
        if (lane == 0) out[b * NO + o] = p;
    }
}
} // namespace

extern "C" void kernel_launch(void* const* d_in, const int* in_sizes, int n_in,
                              void* d_out, int out_size, void* d_ws, size_t ws_size,
                              hipStream_t stream) {
    const float* x     = (const float*)d_in[0];
    const float* cores = (const float*)d_in[1];
    const float* ocp   = (const float*)d_in[2];
    float* out = (float*)d_out;
    float* ws  = (float*)d_ws;       // 64*128 floats = 32 KB
    hipLaunchKernelGGL(mps_chain_kernel, dim3(2 * NB), dim3(64), 0, stream, x, cores, ws);
    hipLaunchKernelGGL(mps_out_kernel,   dim3(NB),     dim3(128), 0, stream, ws, ocp, out);
}